// Round 10
// baseline (1168.285 us; speedup 1.0000x reference)
//
#include <hip/hip_runtime.h>

#define NPTS 262144
#define KVOL 27
#define NPAIRS 65536
#define TP (KVOL*NPAIRS)     // 1769472 pairs
#define CH 64
#define NT32 (NPTS/32)       // 8192 32-row output tiles
#define NSEG (NT32*32)       // 262144 segments (k padded to 32)
#define NBLK2 2048           // conv blocks (4 waves, each owns a 32-row tile)
#define MAXR 12              // max collision rounds; P(exceed) < 1e-9

typedef __attribute__((ext_vector_type(8))) short bf16x8;
typedef __attribute__((ext_vector_type(4))) float f32x4;

__device__ inline unsigned short f2bf(float x){
  unsigned int u = __float_as_uint(x);
  u += 0x7FFFu + ((u >> 16) & 1u);   // RNE
  return (unsigned short)(u >> 16);
}

__device__ inline bf16x8 pack8(float4 a, float4 b){
  bf16x8 r;
  r[0]=(short)f2bf(a.x); r[1]=(short)f2bf(a.y); r[2]=(short)f2bf(a.z); r[3]=(short)f2bf(a.w);
  r[4]=(short)f2bf(b.x); r[5]=(short)f2bf(b.y); r[6]=(short)f2bf(b.z); r[7]=(short)f2bf(b.w);
  return r;
}

// ---- fused: feat->bf16 (bf16 path), weight pack, count + rank capture ----
template<bool BF16G>
__global__ void k_pre(const float* __restrict__ feat, const float* __restrict__ w,
                      const int2* __restrict__ km, unsigned short* __restrict__ featb,
                      unsigned short* __restrict__ wpack, int* __restrict__ cnt,
                      unsigned short* __restrict__ rankb){
  int i = blockIdx.x*256 + threadIdx.x;
  if (BF16G){
    float4 v = ((const float4*)feat)[i];     // grid sized to NPTS*CH/4
    ushort4 r;
    r.x = f2bf(v.x); r.y = f2bf(v.y); r.z = f2bf(v.z); r.w = f2bf(v.w);
    ((ushort4*)featb)[i] = r;
  }
  if (i < TP){
    int2 io = km[i];
    int k = i >> 16;
    int seg = ((io.y >> 5) << 5) | k;
    int rank = atomicAdd(&cnt[seg], 1);
    rankb[i] = (unsigned short)rank;
  }
  if (i < KVOL*CH*CH){
    int j = i & 7, col = (i >> 3) & 63, kb = (i >> 9) & 7, k = i >> 12;
    wpack[i] = f2bf(w[(k*CH + kb*8 + j)*CH + col]);
  }
}

// ---- assign contiguous record ranges per segment (order-free, no scan) ----
__global__ void k_assign(const int* __restrict__ cnt, int* __restrict__ gtot,
                         int2* __restrict__ segd){
  int i = blockIdx.x*256 + threadIdx.x;   // NSEG
  int l = threadIdx.x & 63;
  int c = cnt[i];
  int v = c;
  #pragma unroll
  for (int d = 1; d < 64; d <<= 1){ int u = __shfl_up(v, d, 64); if (l >= d) v += u; }
  int wtot = __shfl(v, 63, 64);
  int base = 0;
  if (l == 63) base = atomicAdd(gtot, wtot);
  base = __shfl(base, 63, 64);
  segd[i] = make_int2(base + v - c, c);
}

// ---- scatter packed records (in:18b | slot:5b) via stored rank, no atomics ----
__global__ void k_scatter(const int2* __restrict__ km, const unsigned short* __restrict__ rankb,
                          const int2* __restrict__ segd, int* __restrict__ records){
  int i = blockIdx.x*256 + threadIdx.x;
  int2 io = km[i];
  int k = i >> 16;
  int seg = ((io.y >> 5) << 5) | k;
  int pos = segd[seg].x + rankb[i];
  records[pos] = io.x | ((io.y & 31) << 18);
}

// ---- conv: wave owns 32 rows; double-buffered LDS slot table; round-0 A prefetch ----
template<bool BF16G>
__global__ __launch_bounds__(256, 4) void k_conv10(
    const unsigned short* __restrict__ featb, const float* __restrict__ featf,
    const unsigned short* __restrict__ wpack, const int* __restrict__ records,
    const int2* __restrict__ segd, float* __restrict__ out, float* __restrict__ partials)
{
  __shared__ int lcnt[4][2][32];
  __shared__ int lslot[4][2][MAXR*32];
  __shared__ float sred[4][2][64];

  int tid = threadIdx.x;
  int wv = tid>>6, l = tid&63, lg = l>>4, li = l&15;
  int t32 = blockIdx.x*4 + wv;      // 32-row tile
  int segbase = t32 << 5;

  const bf16x8* fb = (const bf16x8*)featb;
  const float4* ff = (const float4*)featf;
  const bf16x8* wbase = ((const bf16x8*)wpack) + lg*64 + li;

  f32x4 acc[2][4];
  #pragma unroll
  for (int rt = 0; rt < 2; rt++)
    #pragma unroll
    for (int ct = 0; ct < 4; ct++) acc[rt][ct] = (f32x4)(0.0f);

  auto buildTable = [&](int buf, int rec, int cc){
    if (l < 32) lcnt[wv][buf][l] = 0;
    if (l < cc){
      int slot = (rec >> 18) & 31;
      int rank = atomicAdd(&lcnt[wv][buf][slot], 1);
      if (rank < MAXR) lslot[wv][buf][rank*32 + slot] = rec;
    }
  };
  auto gatherA = [&](int rec, bool v, bf16x8& X0, bf16x8& X1){
    X0 = (bf16x8)(short)0; X1 = (bf16x8)(short)0;
    if (v){
      int in = rec & 0x3FFFF;
      if (BF16G){ X0 = fb[in*8 + lg]; X1 = fb[in*8 + 4 + lg]; }
      else {
        float4 u0 = ff[in*16 + lg*2],     u1 = ff[in*16 + lg*2 + 1];
        float4 u2 = ff[in*16 + 8 + lg*2], u3 = ff[in*16 + 8 + lg*2 + 1];
        X0 = pack8(u0, u1); X1 = pack8(u2, u3);
      }
    }
  };
  auto mfma8 = [&](bf16x8 X0, bf16x8 X1, f32x4 (&arow)[4], bf16x8 (&B)[4][2]){
    #pragma unroll
    for (int ct = 0; ct < 4; ct++){
      arow[ct] = __builtin_amdgcn_mfma_f32_16x16x32_bf16(X0, B[ct][0], arow[ct], 0, 0, 0);
      arow[ct] = __builtin_amdgcn_mfma_f32_16x16x32_bf16(X1, B[ct][1], arow[ct], 0, 0, 0);
    }
  };

  // prologue: table + round-0 prefetch for k=0; records for k=1
  int2 sdA = segd[segbase + 0];
  int2 sdB = segd[segbase + 1];
  int2 sdC = segd[segbase + 2];
  int rec_cur = 0;
  if (l < sdA.y) rec_cur = records[sdA.x + l];
  buildTable(0, rec_cur, min(64, sdA.y));
  int pc0 = min(lcnt[wv][0][li], MAXR), pc1 = min(lcnt[wv][0][16 + li], MAXR);
  bf16x8 P00, P01, P10, P11;
  gatherA(lslot[wv][0][li],      pc0 > 0, P00, P01);
  gatherA(lslot[wv][0][16 + li], pc1 > 0, P10, P11);
  int rec_nx = 0;
  if (l < sdB.y) rec_nx = records[sdB.x + l];

  for (int k = 0; k < KVOL; k++){
    int cb = k & 1, nb = cb ^ 1;

    // 1) build next segment's table + issue its round-0 gathers
    int ncnt0 = 0, ncnt1 = 0;
    bf16x8 N00, N01, N10, N11;
    N00 = N01 = N10 = N11 = (bf16x8)(short)0;
    if (k + 1 < KVOL && sdB.y > 0){
      buildTable(nb, rec_nx, min(64, sdB.y));
      ncnt0 = min(lcnt[wv][nb][li], MAXR);
      ncnt1 = min(lcnt[wv][nb][16 + li], MAXR);
      gatherA(lslot[wv][nb][li],      ncnt0 > 0, N00, N01);
      gatherA(lslot[wv][nb][16 + li], ncnt1 > 0, N10, N11);
    }
    // 2) load records for k+2
    int rec2 = 0;
    if (l < sdC.y) rec2 = records[sdC.x + l];

    // 3) process current segment
    int tot = sdA.y;
    if (tot > 0){
      bf16x8 B[4][2];
      #pragma unroll
      for (int ct = 0; ct < 4; ct++)
        #pragma unroll
        for (int h = 0; h < 2; h++)
          B[ct][h] = wbase[k*512 + h*256 + ct*16];

      // round 0 with prefetched A
      if (__ballot(pc0 > 0)) mfma8(P00, P01, acc[0], B);
      if (__ballot(pc1 > 0)) mfma8(P10, P11, acc[1], B);
      // rounds >= 1 inline (rare)
      for (int r = 1; r < MAXR; r++){
        bool v0 = (r < pc0), v1 = (r < pc1);
        if (__ballot(v0 || v1) == 0ull) break;
        int rr0 = lslot[wv][cb][r*32 + li];
        int rr1 = lslot[wv][cb][r*32 + 16 + li];
        bf16x8 X00, X01, X10, X11;
        gatherA(rr0, v0, X00, X01);
        gatherA(rr1, v1, X10, X11);
        if (__ballot(v0)) mfma8(X00, X01, acc[0], B);
        if (__ballot(v1)) mfma8(X10, X11, acc[1], B);
      }
      // overflow chunks (practically never: P(tot>64) ~ 0)
      for (int c0 = 64; c0 < tot; c0 += 64){
        int cc = min(64, tot - c0);
        int rec = 0;
        if (l < cc) rec = records[sdA.x + c0 + l];
        buildTable(cb, rec, cc);
        int q0 = min(lcnt[wv][cb][li], MAXR), q1 = min(lcnt[wv][cb][16 + li], MAXR);
        for (int r = 0; r < MAXR; r++){
          bool v0 = (r < q0), v1 = (r < q1);
          if (__ballot(v0 || v1) == 0ull) break;
          int rr0 = lslot[wv][cb][r*32 + li];
          int rr1 = lslot[wv][cb][r*32 + 16 + li];
          bf16x8 X00, X01, X10, X11;
          gatherA(rr0, v0, X00, X01);
          gatherA(rr1, v1, X10, X11);
          if (__ballot(v0)) mfma8(X00, X01, acc[0], B);
          if (__ballot(v1)) mfma8(X10, X11, acc[1], B);
        }
      }
    }

    // rotate pipeline state
    sdA = sdB; sdB = sdC; sdC = segd[segbase + min(k + 3, 31)];
    rec_nx = rec2;
    pc0 = ncnt0; pc1 = ncnt1;
    P00 = N00; P01 = N01; P10 = N10; P11 = N11;
  }

  // flush 32x64 rows from registers
  #pragma unroll
  for (int rt = 0; rt < 2; rt++)
    #pragma unroll
    for (int r = 0; r < 4; r++){
      int row = t32*32 + rt*16 + lg*4 + r;
      #pragma unroll
      for (int ct = 0; ct < 4; ct++)
        out[row*CH + ct*16 + li] = acc[rt][ct][r];
    }

  // BN stats partials
  float s1[4], s2[4];
  #pragma unroll
  for (int ct = 0; ct < 4; ct++){
    float a1 = 0.f, a2 = 0.f;
    #pragma unroll
    for (int rt = 0; rt < 2; rt++)
      #pragma unroll
      for (int r = 0; r < 4; r++){
        float v = acc[rt][ct][r];
        a1 += v; a2 += v*v;
      }
    a1 += __shfl_xor(a1, 16, 64); a1 += __shfl_xor(a1, 32, 64);
    a2 += __shfl_xor(a2, 16, 64); a2 += __shfl_xor(a2, 32, 64);
    s1[ct] = a1; s2[ct] = a2;
  }
  __syncthreads();
  if (l < 16){
    #pragma unroll
    for (int ct = 0; ct < 4; ct++){
      sred[wv][0][ct*16 + li] = s1[ct];
      sred[wv][1][ct*16 + li] = s2[ct];
    }
  }
  __syncthreads();
  if (tid < 128){
    int h = tid >> 6, c = tid & 63;
    float p = sred[0][h][c] + sred[1][h][c] + sred[2][h][c] + sred[3][h][c];
    partials[blockIdx.x*128 + tid] = p;
  }
}

// ---- parallel final stats reduce ----
__global__ void k_statred(const float* __restrict__ partials, float* __restrict__ stats){
  __shared__ float sm_[256];
  int c = blockIdx.x;       // 0..127
  int t = threadIdx.x;      // 256
  float s = 0.f;
  for (int b = t; b < NBLK2; b += 256) s += partials[b*128 + c];
  sm_[t] = s;
  __syncthreads();
  for (int d = 128; d > 0; d >>= 1){
    if (t < d) sm_[t] += sm_[t+d];
    __syncthreads();
  }
  if (t == 0) stats[c] = sm_[0];
}

// ---- BN (batch stats, biased var) + ReLU, in place ----
__global__ void k_bn(float* __restrict__ out, const float* __restrict__ stats,
                     const float* __restrict__ g, const float* __restrict__ b){
  int i = blockIdx.x * blockDim.x + threadIdx.x;  // NPTS*CH/4
  float4 v = ((const float4*)out)[i];
  int c0 = (i * 4) & 63;
  float vals[4] = {v.x, v.y, v.z, v.w};
  float res[4];
  #pragma unroll
  for (int q = 0; q < 4; q++){
    int c = c0 + q;
    float mean = stats[c] * (1.0f/NPTS);
    float var  = stats[64+c] * (1.0f/NPTS) - mean*mean;
    float inv  = rsqrtf(var + 1e-5f);
    float y = (vals[q] - mean) * inv * g[c] + b[c];
    res[q] = fmaxf(y, 0.0f);
  }
  float4 r; r.x=res[0]; r.y=res[1]; r.z=res[2]; r.w=res[3];
  ((float4*)out)[i] = r;
}

extern "C" void kernel_launch(void* const* d_in, const int* in_sizes, int n_in,
                              void* d_out, int out_size, void* d_ws, size_t ws_size,
                              hipStream_t stream) {
  const float* feat   = (const float*)d_in[0];
  const int*   kmap   = (const int*)d_in[3];
  const float* weight = (const float*)d_in[4];
  const float* bnw    = (const float*)d_in[5];
  const float* bnb    = (const float*)d_in[6];
  float* out = (float*)d_out;

  char* ws = (char*)d_ws;
  size_t cur = 0;
  auto take = [&](size_t bytes){
    cur = (cur + 255) & ~(size_t)255;
    size_t p = cur; cur += bytes; return p;
  };
  float* stats          = (float*)(ws + take(2*CH*sizeof(float)));
  float* partials       = (float*)(ws + take((size_t)NBLK2*128*sizeof(float)));
  int* cnt              = (int*)(ws + take((size_t)(NSEG+64)*4));   // cnt + cursor at [NSEG]
  int2* segd            = (int2*)(ws + take((size_t)NSEG*8));
  unsigned short* wpack = (unsigned short*)(ws + take((size_t)KVOL*CH*CH*2));
  unsigned short* rankb = (unsigned short*)(ws + take((size_t)TP*2));
  int* records          = (int*)(ws + take((size_t)TP*4));
  size_t featb_off      = take((size_t)NPTS*CH*2);
  bool useBf16 = (ws_size >= cur);
  unsigned short* featb = (unsigned short*)(ws + featb_off);
  int* gtot = cnt + NSEG;

  hipMemsetAsync(cnt, 0, (size_t)(NSEG+64)*4, stream);

  const int2* km = (const int2*)kmap;
  if (useBf16)
    k_pre<true><<<NPTS*CH/4/256, 256, 0, stream>>>(feat, weight, km, featb, wpack, cnt, rankb);
  else
    k_pre<false><<<TP/256, 256, 0, stream>>>(feat, weight, km, featb, wpack, cnt, rankb);

  k_assign<<<NSEG/256, 256, 0, stream>>>(cnt, gtot, segd);
  k_scatter<<<TP/256, 256, 0, stream>>>(km, rankb, segd, records);

  if (useBf16)
    k_conv10<true><<<NBLK2, 256, 0, stream>>>(featb, feat, wpack, records, segd, out, partials);
  else
    k_conv10<false><<<NBLK2, 256, 0, stream>>>(featb, feat, wpack, records, segd, out, partials);

  k_statred<<<128, 256, 0, stream>>>(partials, stats);
  k_bn<<<NPTS*CH/4/256, 256, 0, stream>>>(out, stats, bnw, bnb);
}

// Round 11
// 310.510 us; speedup vs baseline: 3.7625x; 3.7625x over previous
//
#include <hip/hip_runtime.h>

#define NPTS 262144
#define KVOL 27
#define NPAIRS 65536
#define TP (KVOL*NPAIRS)     // 1769472 pairs
#define CH 64
#define NT32 (NPTS/32)       // 8192 32-row output tiles
#define NSEG (NT32*32)       // 262144 segments (k padded to 32)
#define NBLK2 2048           // conv blocks (4 waves, each owns a 32-row tile)
#define MAXR 12              // max collision rounds; P(exceed) < 1e-9

typedef __attribute__((ext_vector_type(8))) short bf16x8;
typedef __attribute__((ext_vector_type(4))) float f32x4;

__device__ inline unsigned short f2bf(float x){
  unsigned int u = __float_as_uint(x);
  u += 0x7FFFu + ((u >> 16) & 1u);   // RNE
  return (unsigned short)(u >> 16);
}

__device__ inline bf16x8 pack8(float4 a, float4 b){
  bf16x8 r;
  r[0]=(short)f2bf(a.x); r[1]=(short)f2bf(a.y); r[2]=(short)f2bf(a.z); r[3]=(short)f2bf(a.w);
  r[4]=(short)f2bf(b.x); r[5]=(short)f2bf(b.y); r[6]=(short)f2bf(b.z); r[7]=(short)f2bf(b.w);
  return r;
}

// direct-to-LDS DMA: per-lane global src, lands at ldsbase + lane*16
__device__ inline void gload16(const void* g, void* l){
  __builtin_amdgcn_global_load_lds(
    (const __attribute__((address_space(1))) void*)g,
    (__attribute__((address_space(3))) void*)l, 16, 0, 0);
}

// ---- fused: feat->bf16 (bf16 path), weight pack, count + rank capture ----
template<bool BF16G>
__global__ void k_pre(const float* __restrict__ feat, const float* __restrict__ w,
                      const int2* __restrict__ km, unsigned short* __restrict__ featb,
                      unsigned short* __restrict__ wpack, int* __restrict__ cnt,
                      unsigned short* __restrict__ rankb){
  int i = blockIdx.x*256 + threadIdx.x;
  if (BF16G){
    float4 v = ((const float4*)feat)[i];     // grid sized to NPTS*CH/4
    ushort4 r;
    r.x = f2bf(v.x); r.y = f2bf(v.y); r.z = f2bf(v.z); r.w = f2bf(v.w);
    ((ushort4*)featb)[i] = r;
  }
  if (i < TP){
    int2 io = km[i];
    int k = i >> 16;
    int seg = ((io.y >> 5) << 5) | k;
    int rank = atomicAdd(&cnt[seg], 1);
    rankb[i] = (unsigned short)rank;
  }
  if (i < KVOL*CH*CH){
    int j = i & 7, col = (i >> 3) & 63, kb = (i >> 9) & 7, k = i >> 12;
    wpack[i] = f2bf(w[(k*CH + kb*8 + j)*CH + col]);
  }
}

// ---- assign contiguous record ranges per segment (order-free, no scan) ----
__global__ void k_assign(const int* __restrict__ cnt, int* __restrict__ gtot,
                         int2* __restrict__ segd){
  int i = blockIdx.x*256 + threadIdx.x;   // NSEG
  int l = threadIdx.x & 63;
  int c = cnt[i];
  int v = c;
  #pragma unroll
  for (int d = 1; d < 64; d <<= 1){ int u = __shfl_up(v, d, 64); if (l >= d) v += u; }
  int wtot = __shfl(v, 63, 64);
  int base = 0;
  if (l == 63) base = atomicAdd(gtot, wtot);
  base = __shfl(base, 63, 64);
  segd[i] = make_int2(base + v - c, c);
}

// ---- scatter packed records (in:18b | slot:5b) via stored rank, no atomics ----
__global__ void k_scatter(const int2* __restrict__ km, const unsigned short* __restrict__ rankb,
                          const int2* __restrict__ segd, int* __restrict__ records){
  int i = blockIdx.x*256 + threadIdx.x;
  int2 io = km[i];
  int k = i >> 16;
  int seg = ((io.y >> 5) << 5) | k;
  int pos = segd[seg].x + rankb[i];
  records[pos] = io.x | ((io.y & 31) << 18);
}

// ---- conv: wave owns 32 rows; round-0 A prefetch via global_load_lds (no VGPR state) ----
template<bool BF16G>
__global__ __launch_bounds__(256, 4) void k_conv11(
    const unsigned short* __restrict__ featb, const float* __restrict__ featf,
    const unsigned short* __restrict__ wpack, const int* __restrict__ records,
    const int2* __restrict__ segd, const unsigned short* __restrict__ zrow,
    float* __restrict__ out, float* __restrict__ partials)
{
  __shared__ int lcnt[4][2][32];
  __shared__ int lslot[4][2][MAXR*32];
  __shared__ float sred[4][2][64];
  __shared__ short pf[4][4][64*8];   // [wave][class][lane*8] : 16KB total

  int tid = threadIdx.x;
  int wv = tid>>6, l = tid&63, lg = l>>4, li = l&15;
  int t32 = blockIdx.x*4 + wv;      // 32-row tile
  int segbase = t32 << 5;

  const bf16x8* fb = (const bf16x8*)featb;
  const float4* ff = (const float4*)featf;
  const bf16x8* wbase = ((const bf16x8*)wpack) + lg*64 + li;

  f32x4 acc[2][4];
  #pragma unroll
  for (int rt = 0; rt < 2; rt++)
    #pragma unroll
    for (int ct = 0; ct < 4; ct++) acc[rt][ct] = (f32x4)(0.0f);

  if (BF16G){
    // ---- prologue: table + DMA for k=0, records for k=1 ----
    int2 sdA = segd[segbase];
    int2 sdB = segd[segbase + 1];
    int2 sdC = segd[segbase + 2];
    int rec0 = 0;
    if (l < sdA.y) rec0 = records[sdA.x + l];
    if (l < 32) lcnt[wv][0][l] = 0;
    int cc0 = min(64, sdA.y);
    if (l < cc0){
      int slot = (rec0 >> 18) & 31;
      int rank = atomicAdd(&lcnt[wv][0][slot], 1);
      if (rank < MAXR) lslot[wv][0][rank*32 + slot] = rec0;
    }
    int pc0 = min(lcnt[wv][0][li], MAXR);
    int pc1 = min(lcnt[wv][0][16 + li], MAXR);
    {
      int in0 = lslot[wv][0][li] & 0x3FFFF;
      int in1 = lslot[wv][0][16 + li] & 0x3FFFF;
      const void* s0 = (pc0 > 0) ? (const void*)&fb[in0*8 + lg]     : (const void*)zrow;
      const void* s1 = (pc0 > 0) ? (const void*)&fb[in0*8 + 4 + lg] : (const void*)zrow;
      const void* s2 = (pc1 > 0) ? (const void*)&fb[in1*8 + lg]     : (const void*)zrow;
      const void* s3 = (pc1 > 0) ? (const void*)&fb[in1*8 + 4 + lg] : (const void*)zrow;
      gload16(s0, &pf[wv][0][0]);
      gload16(s1, &pf[wv][1][0]);
      gload16(s2, &pf[wv][2][0]);
      gload16(s3, &pf[wv][3][0]);
    }
    int rec_nx = 0;
    if (l < sdB.y) rec_nx = records[sdB.x + l];

    for (int k = 0; k < KVOL; k++){
      int cb = k & 1, nb = cb ^ 1;
      // (0) drain DMA + outstanding loads
      asm volatile("s_waitcnt vmcnt(0)" ::: "memory");
      // (1) consume round-0 prefetch (lane reads own 16B)
      bf16x8 A00 = *(const bf16x8*)&pf[wv][0][l*8];
      bf16x8 A01 = *(const bf16x8*)&pf[wv][1][l*8];
      bf16x8 A10 = *(const bf16x8*)&pf[wv][2][l*8];
      bf16x8 A11 = *(const bf16x8*)&pf[wv][3][l*8];
      // (2) B fragments (VMEM, L2-hot)
      int tot = sdA.y;
      bf16x8 B[4][2];
      if (tot > 0){
        #pragma unroll
        for (int ct = 0; ct < 4; ct++)
          #pragma unroll
          for (int h = 0; h < 2; h++)
            B[ct][h] = wbase[k*512 + h*256 + ct*16];
      }
      // (3) build k+1 table, issue its round-0 DMA
      int ncnt0 = 0, ncnt1 = 0;
      if (sdB.y > 0){
        if (l < 32) lcnt[wv][nb][l] = 0;
        int cc = min(64, sdB.y);
        if (l < cc){
          int slot = (rec_nx >> 18) & 31;
          int rank = atomicAdd(&lcnt[wv][nb][slot], 1);
          if (rank < MAXR) lslot[wv][nb][rank*32 + slot] = rec_nx;
        }
        ncnt0 = min(lcnt[wv][nb][li], MAXR);
        ncnt1 = min(lcnt[wv][nb][16 + li], MAXR);
        int in0 = lslot[wv][nb][li] & 0x3FFFF;
        int in1 = lslot[wv][nb][16 + li] & 0x3FFFF;
        const void* s0 = (ncnt0 > 0) ? (const void*)&fb[in0*8 + lg]     : (const void*)zrow;
        const void* s1 = (ncnt0 > 0) ? (const void*)&fb[in0*8 + 4 + lg] : (const void*)zrow;
        const void* s2 = (ncnt1 > 0) ? (const void*)&fb[in1*8 + lg]     : (const void*)zrow;
        const void* s3 = (ncnt1 > 0) ? (const void*)&fb[in1*8 + 4 + lg] : (const void*)zrow;
        // consumption ds_reads must drain before DMA may overwrite pf
        asm volatile("s_waitcnt lgkmcnt(0)" ::: "memory");
        gload16(s0, &pf[wv][0][0]);
        gload16(s1, &pf[wv][1][0]);
        gload16(s2, &pf[wv][2][0]);
        gload16(s3, &pf[wv][3][0]);
      }
      // (4) records for k+2
      int rec2 = 0;
      if (l < sdC.y) rec2 = records[sdC.x + l];
      // (5) compute segment k
      if (tot > 0){
        if (__ballot(pc0 > 0)){
          #pragma unroll
          for (int ct = 0; ct < 4; ct++){
            acc[0][ct] = __builtin_amdgcn_mfma_f32_16x16x32_bf16(A00, B[ct][0], acc[0][ct], 0, 0, 0);
            acc[0][ct] = __builtin_amdgcn_mfma_f32_16x16x32_bf16(A01, B[ct][1], acc[0][ct], 0, 0, 0);
          }
        }
        if (__ballot(pc1 > 0)){
          #pragma unroll
          for (int ct = 0; ct < 4; ct++){
            acc[1][ct] = __builtin_amdgcn_mfma_f32_16x16x32_bf16(A10, B[ct][0], acc[1][ct], 0, 0, 0);
            acc[1][ct] = __builtin_amdgcn_mfma_f32_16x16x32_bf16(A11, B[ct][1], acc[1][ct], 0, 0, 0);
          }
        }
        // rounds >= 1 (rare), serial gathers
        for (int r = 1; r < MAXR; r++){
          bool v0 = (r < pc0), v1 = (r < pc1);
          if (__ballot(v0 || v1) == 0ull) break;
          int rr0 = lslot[wv][cb][r*32 + li];
          int rr1 = lslot[wv][cb][r*32 + 16 + li];
          bf16x8 X00 = (bf16x8)(short)0, X01 = (bf16x8)(short)0;
          bf16x8 X10 = (bf16x8)(short)0, X11 = (bf16x8)(short)0;
          if (v0){ int in = rr0 & 0x3FFFF; X00 = fb[in*8 + lg]; X01 = fb[in*8 + 4 + lg]; }
          if (v1){ int in = rr1 & 0x3FFFF; X10 = fb[in*8 + lg]; X11 = fb[in*8 + 4 + lg]; }
          if (__ballot(v0)){
            #pragma unroll
            for (int ct = 0; ct < 4; ct++){
              acc[0][ct] = __builtin_amdgcn_mfma_f32_16x16x32_bf16(X00, B[ct][0], acc[0][ct], 0, 0, 0);
              acc[0][ct] = __builtin_amdgcn_mfma_f32_16x16x32_bf16(X01, B[ct][1], acc[0][ct], 0, 0, 0);
            }
          }
          if (__ballot(v1)){
            #pragma unroll
            for (int ct = 0; ct < 4; ct++){
              acc[1][ct] = __builtin_amdgcn_mfma_f32_16x16x32_bf16(X10, B[ct][0], acc[1][ct], 0, 0, 0);
              acc[1][ct] = __builtin_amdgcn_mfma_f32_16x16x32_bf16(X11, B[ct][1], acc[1][ct], 0, 0, 0);
            }
          }
        }
        // overflow chunks (practically never)
        for (int c0 = 64; c0 < tot; c0 += 64){
          int cc = min(64, tot - c0);
          int rec = 0;
          if (l < cc) rec = records[sdA.x + c0 + l];
          if (l < 32) lcnt[wv][cb][l] = 0;
          if (l < cc){
            int slot = (rec >> 18) & 31;
            int rank = atomicAdd(&lcnt[wv][cb][slot], 1);
            if (rank < MAXR) lslot[wv][cb][rank*32 + slot] = rec;
          }
          int q0 = min(lcnt[wv][cb][li], MAXR), q1 = min(lcnt[wv][cb][16 + li], MAXR);
          for (int r = 0; r < MAXR; r++){
            bool v0 = (r < q0), v1 = (r < q1);
            if (__ballot(v0 || v1) == 0ull) break;
            int rr0 = lslot[wv][cb][r*32 + li];
            int rr1 = lslot[wv][cb][r*32 + 16 + li];
            bf16x8 X00 = (bf16x8)(short)0, X01 = (bf16x8)(short)0;
            bf16x8 X10 = (bf16x8)(short)0, X11 = (bf16x8)(short)0;
            if (v0){ int in = rr0 & 0x3FFFF; X00 = fb[in*8 + lg]; X01 = fb[in*8 + 4 + lg]; }
            if (v1){ int in = rr1 & 0x3FFFF; X10 = fb[in*8 + lg]; X11 = fb[in*8 + 4 + lg]; }
            if (__ballot(v0)){
              #pragma unroll
              for (int ct = 0; ct < 4; ct++){
                acc[0][ct] = __builtin_amdgcn_mfma_f32_16x16x32_bf16(X00, B[ct][0], acc[0][ct], 0, 0, 0);
                acc[0][ct] = __builtin_amdgcn_mfma_f32_16x16x32_bf16(X01, B[ct][1], acc[0][ct], 0, 0, 0);
              }
            }
            if (__ballot(v1)){
              #pragma unroll
              for (int ct = 0; ct < 4; ct++){
                acc[1][ct] = __builtin_amdgcn_mfma_f32_16x16x32_bf16(X10, B[ct][0], acc[1][ct], 0, 0, 0);
                acc[1][ct] = __builtin_amdgcn_mfma_f32_16x16x32_bf16(X11, B[ct][1], acc[1][ct], 0, 0, 0);
              }
            }
          }
        }
      }
      // rotate
      sdA = sdB; sdB = sdC; sdC = segd[segbase + min(k + 3, 31)];
      rec_nx = rec2;
      pc0 = ncnt0; pc1 = ncnt1;
    }
  } else {
    // ---- fp32 fallback: R6-style serial loop ----
    int2 sd  = segd[segbase];
    int2 sd1 = segd[segbase + 1];
    int rec_pf = 0;
    if (l < sd.y) rec_pf = records[sd.x + l];
    for (int k = 0; k < KVOL; k++){
      int2 sd2 = segd[segbase + min(k + 2, 31)];
      int rec_nx = 0;
      if (l < sd1.y) rec_nx = records[sd1.x + l];
      int beg = sd.x, tot = sd.y;
      if (tot > 0){
        bf16x8 B[4][2];
        #pragma unroll
        for (int ct = 0; ct < 4; ct++)
          #pragma unroll
          for (int h = 0; h < 2; h++)
            B[ct][h] = wbase[k*512 + h*256 + ct*16];
        int rec = rec_pf;
        for (int c0 = 0; c0 < tot; c0 += 64){
          int cc = min(64, tot - c0);
          if (c0 > 0 && l < cc) rec = records[beg + c0 + l];
          if (l < 32) lcnt[wv][0][l] = 0;
          if (l < cc){
            int slot = (rec >> 18) & 31;
            int rank = atomicAdd(&lcnt[wv][0][slot], 1);
            if (rank < MAXR) lslot[wv][0][rank*32 + slot] = rec;
          }
          int q0 = min(lcnt[wv][0][li], MAXR), q1 = min(lcnt[wv][0][16 + li], MAXR);
          for (int r = 0; r < MAXR; r++){
            bool v0 = (r < q0), v1 = (r < q1);
            if (__ballot(v0 || v1) == 0ull) break;
            int rr0 = lslot[wv][0][r*32 + li];
            int rr1 = lslot[wv][0][r*32 + 16 + li];
            bf16x8 X00 = (bf16x8)(short)0, X01 = (bf16x8)(short)0;
            bf16x8 X10 = (bf16x8)(short)0, X11 = (bf16x8)(short)0;
            if (v0){
              int in = rr0 & 0x3FFFF;
              float4 u0 = ff[in*16 + lg*2],     u1 = ff[in*16 + lg*2 + 1];
              float4 u2 = ff[in*16 + 8 + lg*2], u3 = ff[in*16 + 8 + lg*2 + 1];
              X00 = pack8(u0, u1); X01 = pack8(u2, u3);
            }
            if (v1){
              int in = rr1 & 0x3FFFF;
              float4 u0 = ff[in*16 + lg*2],     u1 = ff[in*16 + lg*2 + 1];
              float4 u2 = ff[in*16 + 8 + lg*2], u3 = ff[in*16 + 8 + lg*2 + 1];
              X10 = pack8(u0, u1); X11 = pack8(u2, u3);
            }
            if (__ballot(v0)){
              #pragma unroll
              for (int ct = 0; ct < 4; ct++){
                acc[0][ct] = __builtin_amdgcn_mfma_f32_16x16x32_bf16(X00, B[ct][0], acc[0][ct], 0, 0, 0);
                acc[0][ct] = __builtin_amdgcn_mfma_f32_16x16x32_bf16(X01, B[ct][1], acc[0][ct], 0, 0, 0);
              }
            }
            if (__ballot(v1)){
              #pragma unroll
              for (int ct = 0; ct < 4; ct++){
                acc[1][ct] = __builtin_amdgcn_mfma_f32_16x16x32_bf16(X10, B[ct][0], acc[1][ct], 0, 0, 0);
                acc[1][ct] = __builtin_amdgcn_mfma_f32_16x16x32_bf16(X11, B[ct][1], acc[1][ct], 0, 0, 0);
              }
            }
          }
        }
      }
      rec_pf = rec_nx; sd = sd1; sd1 = sd2;
    }
  }

  // flush 32x64 rows from registers
  #pragma unroll
  for (int rt = 0; rt < 2; rt++)
    #pragma unroll
    for (int r = 0; r < 4; r++){
      int row = t32*32 + rt*16 + lg*4 + r;
      #pragma unroll
      for (int ct = 0; ct < 4; ct++)
        out[row*CH + ct*16 + li] = acc[rt][ct][r];
    }

  // BN stats partials
  float s1[4], s2[4];
  #pragma unroll
  for (int ct = 0; ct < 4; ct++){
    float a1 = 0.f, a2 = 0.f;
    #pragma unroll
    for (int rt = 0; rt < 2; rt++)
      #pragma unroll
      for (int r = 0; r < 4; r++){
        float v = acc[rt][ct][r];
        a1 += v; a2 += v*v;
      }
    a1 += __shfl_xor(a1, 16, 64); a1 += __shfl_xor(a1, 32, 64);
    a2 += __shfl_xor(a2, 16, 64); a2 += __shfl_xor(a2, 32, 64);
    s1[ct] = a1; s2[ct] = a2;
  }
  __syncthreads();
  if (l < 16){
    #pragma unroll
    for (int ct = 0; ct < 4; ct++){
      sred[wv][0][ct*16 + li] = s1[ct];
      sred[wv][1][ct*16 + li] = s2[ct];
    }
  }
  __syncthreads();
  if (tid < 128){
    int h = tid >> 6, c = tid & 63;
    float p = sred[0][h][c] + sred[1][h][c] + sred[2][h][c] + sred[3][h][c];
    partials[blockIdx.x*128 + tid] = p;
  }
}

// ---- parallel final stats reduce ----
__global__ void k_statred(const float* __restrict__ partials, float* __restrict__ stats){
  __shared__ float sm_[256];
  int c = blockIdx.x;       // 0..127
  int t = threadIdx.x;      // 256
  float s = 0.f;
  for (int b = t; b < NBLK2; b += 256) s += partials[b*128 + c];
  sm_[t] = s;
  __syncthreads();
  for (int d = 128; d > 0; d >>= 1){
    if (t < d) sm_[t] += sm_[t+d];
    __syncthreads();
  }
  if (t == 0) stats[c] = sm_[0];
}

// ---- BN (batch stats, biased var) + ReLU, in place ----
__global__ void k_bn(float* __restrict__ out, const float* __restrict__ stats,
                     const float* __restrict__ g, const float* __restrict__ b){
  int i = blockIdx.x * blockDim.x + threadIdx.x;  // NPTS*CH/4
  float4 v = ((const float4*)out)[i];
  int c0 = (i * 4) & 63;
  float vals[4] = {v.x, v.y, v.z, v.w};
  float res[4];
  #pragma unroll
  for (int q = 0; q < 4; q++){
    int c = c0 + q;
    float mean = stats[c] * (1.0f/NPTS);
    float var  = stats[64+c] * (1.0f/NPTS) - mean*mean;
    float inv  = rsqrtf(var + 1e-5f);
    float y = (vals[q] - mean) * inv * g[c] + b[c];
    res[q] = fmaxf(y, 0.0f);
  }
  float4 r; r.x=res[0]; r.y=res[1]; r.z=res[2]; r.w=res[3];
  ((float4*)out)[i] = r;
}

extern "C" void kernel_launch(void* const* d_in, const int* in_sizes, int n_in,
                              void* d_out, int out_size, void* d_ws, size_t ws_size,
                              hipStream_t stream) {
  const float* feat   = (const float*)d_in[0];
  const int*   kmap   = (const int*)d_in[3];
  const float* weight = (const float*)d_in[4];
  const float* bnw    = (const float*)d_in[5];
  const float* bnb    = (const float*)d_in[6];
  float* out = (float*)d_out;

  char* ws = (char*)d_ws;
  size_t cur = 0;
  auto take = [&](size_t bytes){
    cur = (cur + 255) & ~(size_t)255;
    size_t p = cur; cur += bytes; return p;
  };
  float* stats          = (float*)(ws + take(2*CH*sizeof(float)));
  float* partials       = (float*)(ws + take((size_t)NBLK2*128*sizeof(float)));
  int* cnt              = (int*)(ws + take((size_t)(NSEG+128)*4));  // cnt + gtot + zrow
  int2* segd            = (int2*)(ws + take((size_t)NSEG*8));
  unsigned short* wpack = (unsigned short*)(ws + take((size_t)KVOL*CH*CH*2));
  unsigned short* rankb = (unsigned short*)(ws + take((size_t)TP*2));
  int* records          = (int*)(ws + take((size_t)TP*4));
  size_t featb_off      = take((size_t)NPTS*CH*2);
  bool useBf16 = (ws_size >= cur);
  unsigned short* featb = (unsigned short*)(ws + featb_off);
  int* gtot = cnt + NSEG;
  const unsigned short* zrow = (const unsigned short*)(cnt + NSEG + 64);  // 128B zeros

  hipMemsetAsync(cnt, 0, (size_t)(NSEG+128)*4, stream);

  const int2* km = (const int2*)kmap;
  if (useBf16)
    k_pre<true><<<NPTS*CH/4/256, 256, 0, stream>>>(feat, weight, km, featb, wpack, cnt, rankb);
  else
    k_pre<false><<<TP/256, 256, 0, stream>>>(feat, weight, km, featb, wpack, cnt, rankb);

  k_assign<<<NSEG/256, 256, 0, stream>>>(cnt, gtot, segd);
  k_scatter<<<TP/256, 256, 0, stream>>>(km, rankb, segd, records);

  if (useBf16)
    k_conv11<true><<<NBLK2, 256, 0, stream>>>(featb, feat, wpack, records, segd, zrow, out, partials);
  else
    k_conv11<false><<<NBLK2, 256, 0, stream>>>(featb, feat, wpack, records, segd, zrow, out, partials);

  k_statred<<<128, 256, 0, stream>>>(partials, stats);
  k_bn<<<NPTS*CH/4/256, 256, 0, stream>>>(out, stats, bnw, bnb);
}

// Round 12
// 269.124 us; speedup vs baseline: 4.3411x; 1.1538x over previous
//
#include <hip/hip_runtime.h>

#define NPTS 262144
#define KVOL 27
#define NPAIRS 65536
#define TP (KVOL*NPAIRS)     // 1769472 pairs
#define CH 64
#define NT32 (NPTS/32)       // 8192 32-row output tiles
#define NSEG (NT32*32)       // 262144 segments (k padded to 32)
#define NBLK2 2048           // conv blocks (4 waves, each owns a 32-row tile)
#define MAXR 12              // max collision rounds per (seg,slot); P(exceed) ~ 0
#define SPILLMAX 131072      // spill capacity (entries)

typedef __attribute__((ext_vector_type(8))) short bf16x8;
typedef __attribute__((ext_vector_type(4))) float f32x4;

__device__ inline unsigned short f2bf(float x){
  unsigned int u = __float_as_uint(x);
  u += 0x7FFFu + ((u >> 16) & 1u);   // RNE
  return (unsigned short)(u >> 16);
}

__device__ inline bf16x8 pack8(float4 a, float4 b){
  bf16x8 r;
  r[0]=(short)f2bf(a.x); r[1]=(short)f2bf(a.y); r[2]=(short)f2bf(a.z); r[3]=(short)f2bf(a.w);
  r[4]=(short)f2bf(b.x); r[5]=(short)f2bf(b.y); r[6]=(short)f2bf(b.z); r[7]=(short)f2bf(b.w);
  return r;
}

// ---- fused: feat->bf16 (bf16 path), weight pack, count + DIRECT bin write ----
template<bool BF16G>
__global__ void k_pre2(const float* __restrict__ feat, const float* __restrict__ w,
                       const int2* __restrict__ km, unsigned short* __restrict__ featb,
                       unsigned short* __restrict__ wpack, int* __restrict__ cnt,
                       int* __restrict__ records, int2* __restrict__ spill,
                       int* __restrict__ spillcnt, int C){
  int i = blockIdx.x*256 + threadIdx.x;
  if (BF16G){
    float4 v = ((const float4*)feat)[i];     // grid sized to NPTS*CH/4
    ushort4 r;
    r.x = f2bf(v.x); r.y = f2bf(v.y); r.z = f2bf(v.z); r.w = f2bf(v.w);
    ((ushort4*)featb)[i] = r;
  }
  if (i < TP){
    int2 io = km[i];
    int k = i >> 16;
    int seg = ((io.y >> 5) << 5) | k;
    int rank = atomicAdd(&cnt[seg], 1);
    int rec = io.x | ((io.y & 31) << 18);
    if (rank < C) records[seg*C + rank] = rec;
    else {
      int sp = atomicAdd(spillcnt, 1);
      if (sp < SPILLMAX) spill[sp] = make_int2(seg, rec);
    }
  }
  if (i < KVOL*CH*CH){
    int j = i & 7, col = (i >> 3) & 63, kb = (i >> 9) & 7, k = i >> 12;
    wpack[i] = f2bf(w[(k*CH + kb*8 + j)*CH + col]);
  }
}

// ---- conv: wave owns 32 rows; binned records; LDS slot table; reg acc ----
template<bool BF16G>
__global__ __launch_bounds__(256, 4) void k_conv12(
    const unsigned short* __restrict__ featb, const float* __restrict__ featf,
    const unsigned short* __restrict__ wpack, const int* __restrict__ records,
    const int* __restrict__ cnt, const int2* __restrict__ spill,
    const int* __restrict__ spillcnt, int C,
    float* __restrict__ out, float* __restrict__ partials)
{
  __shared__ int lcnt[4][32];
  __shared__ int lslot[4][MAXR*32];
  __shared__ float sred[4][2][64];

  int tid = threadIdx.x;
  int wv = tid>>6, l = tid&63, lg = l>>4, li = l&15;
  int t32 = blockIdx.x*4 + wv;      // 32-row tile
  int segbase = t32 << 5;

  const bf16x8* fb = (const bf16x8*)featb;
  const float4* ff = (const float4*)featf;
  const bf16x8* wbase = ((const bf16x8*)wpack) + lg*64 + li;

  f32x4 acc[2][4];
  #pragma unroll
  for (int rt = 0; rt < 2; rt++)
    #pragma unroll
    for (int ct = 0; ct < 4; ct++) acc[rt][ct] = (f32x4)(0.0f);

  // all 27 segment counts in one lane-load
  int myc = (l < KVOL) ? cnt[segbase + l] : 0;

  int tot_cur = __builtin_amdgcn_readlane(myc, 0);
  int rec_pf = 0;
  if (l < min(tot_cur, C)) rec_pf = records[segbase*C + l];

  for (int k = 0; k < KVOL; k++){
    int tot = tot_cur;
    int tot_nx = (k < KVOL-1) ? __builtin_amdgcn_readlane(myc, k+1) : 0;
    int rec_nx = 0;
    if (l < min(tot_nx, C)) rec_nx = records[(segbase + k + 1)*C + l];

    if (tot > 0){
      // B fragments for offset k (L2-hot)
      bf16x8 B[4][2];
      #pragma unroll
      for (int ct = 0; ct < 4; ct++)
        #pragma unroll
        for (int h = 0; h < 2; h++)
          B[ct][h] = wbase[k*512 + h*256 + ct*16];

      // slot table from prefetched bin records
      if (l < 32) lcnt[wv][l] = 0;
      int bcnt = min(tot, C);
      if (l < bcnt){
        int slot = (rec_pf >> 18) & 31;
        int rank = atomicAdd(&lcnt[wv][slot], 1);
        if (rank < MAXR) lslot[wv][rank*32 + slot] = rec_pf;
      }
      int cnt0 = min(lcnt[wv][li], MAXR);
      int cnt1 = min(lcnt[wv][16 + li], MAXR);

      for (int r = 0; r < MAXR; r++){
        bool v0 = (r < cnt0), v1 = (r < cnt1);
        if (__ballot(v0 || v1) == 0ull) break;
        int rr0 = lslot[wv][r*32 + li];
        int rr1 = lslot[wv][r*32 + 16 + li];
        bf16x8 X00 = (bf16x8)(short)0, X01 = (bf16x8)(short)0;
        bf16x8 X10 = (bf16x8)(short)0, X11 = (bf16x8)(short)0;
        if (v0){
          int in = rr0 & 0x3FFFF;
          if (BF16G){ X00 = fb[in*8 + lg]; X01 = fb[in*8 + 4 + lg]; }
          else {
            float4 u0 = ff[in*16 + lg*2],     u1 = ff[in*16 + lg*2 + 1];
            float4 u2 = ff[in*16 + 8 + lg*2], u3 = ff[in*16 + 8 + lg*2 + 1];
            X00 = pack8(u0, u1); X01 = pack8(u2, u3);
          }
        }
        if (v1){
          int in = rr1 & 0x3FFFF;
          if (BF16G){ X10 = fb[in*8 + lg]; X11 = fb[in*8 + 4 + lg]; }
          else {
            float4 u0 = ff[in*16 + lg*2],     u1 = ff[in*16 + lg*2 + 1];
            float4 u2 = ff[in*16 + 8 + lg*2], u3 = ff[in*16 + 8 + lg*2 + 1];
            X10 = pack8(u0, u1); X11 = pack8(u2, u3);
          }
        }
        if (__ballot(v0)){
          #pragma unroll
          for (int ct = 0; ct < 4; ct++){
            acc[0][ct] = __builtin_amdgcn_mfma_f32_16x16x32_bf16(X00, B[ct][0], acc[0][ct], 0, 0, 0);
            acc[0][ct] = __builtin_amdgcn_mfma_f32_16x16x32_bf16(X01, B[ct][1], acc[0][ct], 0, 0, 0);
          }
        }
        if (__ballot(v1)){
          #pragma unroll
          for (int ct = 0; ct < 4; ct++){
            acc[1][ct] = __builtin_amdgcn_mfma_f32_16x16x32_bf16(X10, B[ct][0], acc[1][ct], 0, 0, 0);
            acc[1][ct] = __builtin_amdgcn_mfma_f32_16x16x32_bf16(X11, B[ct][1], acc[1][ct], 0, 0, 0);
          }
        }
      }
    }
    rec_pf = rec_nx; tot_cur = tot_nx;
  }

  // ---- spill pairs (rank >= C in k_pre2): correct, ~never hot ----
  int nsp = min(spillcnt[0], SPILLMAX);
  for (int s0 = 0; s0 < nsp; s0 += 64){
    int idx = s0 + l;
    int2 e = make_int2(-1, 0);
    if (idx < nsp) e = spill[idx];
    unsigned long long m = __ballot((e.x >= 0) && ((e.x >> 5) == t32));
    while (m){
      int j = __ffsll((long long)m) - 1; m &= m - 1;
      int sj = __shfl(e.x, j, 64);
      int rj = __shfl(e.y, j, 64);
      int kk = sj & 31;
      int slot = (rj >> 18) & 31, hh = slot >> 4, sl = slot & 15;
      bf16x8 Bs[4][2];
      #pragma unroll
      for (int ct = 0; ct < 4; ct++)
        #pragma unroll
        for (int h = 0; h < 2; h++)
          Bs[ct][h] = wbase[kk*512 + h*256 + ct*16];
      bool v = (li == sl);
      bf16x8 X0 = (bf16x8)(short)0, X1 = (bf16x8)(short)0;
      if (v){
        int in = rj & 0x3FFFF;
        if (BF16G){ X0 = fb[in*8 + lg]; X1 = fb[in*8 + 4 + lg]; }
        else {
          float4 u0 = ff[in*16 + lg*2],     u1 = ff[in*16 + lg*2 + 1];
          float4 u2 = ff[in*16 + 8 + lg*2], u3 = ff[in*16 + 8 + lg*2 + 1];
          X0 = pack8(u0, u1); X1 = pack8(u2, u3);
        }
      }
      if (hh == 0){
        #pragma unroll
        for (int ct = 0; ct < 4; ct++){
          acc[0][ct] = __builtin_amdgcn_mfma_f32_16x16x32_bf16(X0, Bs[ct][0], acc[0][ct], 0, 0, 0);
          acc[0][ct] = __builtin_amdgcn_mfma_f32_16x16x32_bf16(X1, Bs[ct][1], acc[0][ct], 0, 0, 0);
        }
      } else {
        #pragma unroll
        for (int ct = 0; ct < 4; ct++){
          acc[1][ct] = __builtin_amdgcn_mfma_f32_16x16x32_bf16(X0, Bs[ct][0], acc[1][ct], 0, 0, 0);
          acc[1][ct] = __builtin_amdgcn_mfma_f32_16x16x32_bf16(X1, Bs[ct][1], acc[1][ct], 0, 0, 0);
        }
      }
    }
  }

  // flush 32x64 rows from registers
  #pragma unroll
  for (int rt = 0; rt < 2; rt++)
    #pragma unroll
    for (int r = 0; r < 4; r++){
      int row = t32*32 + rt*16 + lg*4 + r;
      #pragma unroll
      for (int ct = 0; ct < 4; ct++)
        out[row*CH + ct*16 + li] = acc[rt][ct][r];
    }

  // BN stats partials
  float s1[4], s2[4];
  #pragma unroll
  for (int ct = 0; ct < 4; ct++){
    float a1 = 0.f, a2 = 0.f;
    #pragma unroll
    for (int rt = 0; rt < 2; rt++)
      #pragma unroll
      for (int r = 0; r < 4; r++){
        float v = acc[rt][ct][r];
        a1 += v; a2 += v*v;
      }
    a1 += __shfl_xor(a1, 16, 64); a1 += __shfl_xor(a1, 32, 64);
    a2 += __shfl_xor(a2, 16, 64); a2 += __shfl_xor(a2, 32, 64);
    s1[ct] = a1; s2[ct] = a2;
  }
  __syncthreads();
  if (l < 16){
    #pragma unroll
    for (int ct = 0; ct < 4; ct++){
      sred[wv][0][ct*16 + li] = s1[ct];
      sred[wv][1][ct*16 + li] = s2[ct];
    }
  }
  __syncthreads();
  if (tid < 128){
    int h = tid >> 6, c = tid & 63;
    float p = sred[0][h][c] + sred[1][h][c] + sred[2][h][c] + sred[3][h][c];
    partials[blockIdx.x*128 + tid] = p;
  }
}

// ---- parallel final stats reduce ----
__global__ void k_statred(const float* __restrict__ partials, float* __restrict__ stats){
  __shared__ float sm_[256];
  int c = blockIdx.x;       // 0..127
  int t = threadIdx.x;      // 256
  float s = 0.f;
  for (int b = t; b < NBLK2; b += 256) s += partials[b*128 + c];
  sm_[t] = s;
  __syncthreads();
  for (int d = 128; d > 0; d >>= 1){
    if (t < d) sm_[t] += sm_[t+d];
    __syncthreads();
  }
  if (t == 0) stats[c] = sm_[0];
}

// ---- BN (batch stats, biased var) + ReLU, in place ----
__global__ void k_bn(float* __restrict__ out, const float* __restrict__ stats,
                     const float* __restrict__ g, const float* __restrict__ b){
  int i = blockIdx.x * blockDim.x + threadIdx.x;  // NPTS*CH/4
  float4 v = ((const float4*)out)[i];
  int c0 = (i * 4) & 63;
  float vals[4] = {v.x, v.y, v.z, v.w};
  float res[4];
  #pragma unroll
  for (int q = 0; q < 4; q++){
    int c = c0 + q;
    float mean = stats[c] * (1.0f/NPTS);
    float var  = stats[64+c] * (1.0f/NPTS) - mean*mean;
    float inv  = rsqrtf(var + 1e-5f);
    float y = (vals[q] - mean) * inv * g[c] + b[c];
    res[q] = fmaxf(y, 0.0f);
  }
  float4 r; r.x=res[0]; r.y=res[1]; r.z=res[2]; r.w=res[3];
  ((float4*)out)[i] = r;
}

extern "C" void kernel_launch(void* const* d_in, const int* in_sizes, int n_in,
                              void* d_out, int out_size, void* d_ws, size_t ws_size,
                              hipStream_t stream) {
  const float* feat   = (const float*)d_in[0];
  const int*   kmap   = (const int*)d_in[3];
  const float* weight = (const float*)d_in[4];
  const float* bnw    = (const float*)d_in[5];
  const float* bnb    = (const float*)d_in[6];
  float* out = (float*)d_out;

  char* ws = (char*)d_ws;
  size_t cur = 0;
  auto take = [&](size_t bytes){
    cur = (cur + 255) & ~(size_t)255;
    size_t p = cur; cur += bytes; return p;
  };
  float* stats          = (float*)(ws + take(2*CH*sizeof(float)));
  float* partials       = (float*)(ws + take((size_t)NBLK2*128*sizeof(float)));
  int* cnt              = (int*)(ws + take((size_t)(NSEG+64)*4));   // + spillcnt at [NSEG]
  int2* spill           = (int2*)(ws + take((size_t)SPILLMAX*8));
  unsigned short* wpack = (unsigned short*)(ws + take((size_t)KVOL*CH*CH*2));
  size_t base = cur;
  // choose bin capacity C from remaining workspace (featb needed for bf16 path)
  size_t featb_bytes = (size_t)NPTS*CH*2;
  int C = 16;
  bool useBf16 = false;
  {
    size_t avail = (ws_size > base + featb_bytes + 512) ? (ws_size - base - featb_bytes - 512) : 0;
    size_t cmax = avail / ((size_t)NSEG*4);
    if (cmax >= 11){ useBf16 = true; C = (int)((cmax < 16) ? cmax : 16); }
  }
  int* records          = (int*)(ws + take((size_t)NSEG*(useBf16 ? C : 16)*4));
  if (!useBf16) C = 16;
  unsigned short* featb = (unsigned short*)(ws + take(featb_bytes));
  int* spillcnt = cnt + NSEG;

  hipMemsetAsync(cnt, 0, (size_t)(NSEG+64)*4, stream);

  const int2* km = (const int2*)kmap;
  if (useBf16)
    k_pre2<true><<<NPTS*CH/4/256, 256, 0, stream>>>(feat, weight, km, featb, wpack, cnt,
                                                    records, spill, spillcnt, C);
  else
    k_pre2<false><<<TP/256, 256, 0, stream>>>(feat, weight, km, featb, wpack, cnt,
                                              records, spill, spillcnt, C);

  if (useBf16)
    k_conv12<true><<<NBLK2, 256, 0, stream>>>(featb, feat, wpack, records, cnt, spill,
                                              spillcnt, C, out, partials);
  else
    k_conv12<false><<<NBLK2, 256, 0, stream>>>(featb, feat, wpack, records, cnt, spill,
                                               spillcnt, C, out, partials);

  k_statred<<<128, 256, 0, stream>>>(partials, stats);
  k_bn<<<NPTS*CH/4/256, 256, 0, stream>>>(out, stats, bnw, bnb);
}